// Round 3
// baseline (3470.197 us; speedup 1.0000x reference)
//
#include <hip/hip_runtime.h>

#define B 4096
#define T 2048
#define H 64
#define NBATCH 8
#define NB (B / NBATCH)   // 512 blocks, 8 batches each, 4 waves -> 2 blocks/CU

typedef __attribute__((ext_vector_type(8))) short short8;
typedef __attribute__((ext_vector_type(4))) short short4v;
typedef __attribute__((ext_vector_type(4))) float f32x4;

__device__ __forceinline__ float ex2(float x) { return __builtin_amdgcn_exp2f(x); }
__device__ __forceinline__ float sigm(float x) {
    return __builtin_amdgcn_rcpf(1.0f + ex2(-1.4426950408889634f * x));
}
__device__ __forceinline__ float tanh_(float x) {
    float xc = fminf(15.0f, fmaxf(-15.0f, x));
    float e = ex2(2.8853900817779268f * xc);         // e^(2x)
    return (e - 1.0f) * __builtin_amdgcn_rcpf(e + 1.0f);
}
__device__ __forceinline__ unsigned short f2bf(float f) {  // RNE f32->bf16
    unsigned u = __builtin_bit_cast(unsigned, f);
    u += 0x7fffu + ((u >> 16) & 1u);
    return (unsigned short)(u >> 16);
}

// ---------------------------------------------------------------------------
// Encoder: 512 blocks x 8 batches (2 blocks/CU -> 2 waves/SIMD latency hiding).
// A = Whh tile (regs), B = h (LDS). C: row=unit, col=batch (cols 0-7 valid;
// lanes lo>=8 shadow batch lo-8, writes masked). Unroll x4: static parity.
// ---------------------------------------------------------------------------
extern "C" __global__ void __launch_bounds__(256, 2)
enc_kernel(const float* __restrict__ padded, const int* __restrict__ seq_len,
           const float* __restrict__ Wih, const float* __restrict__ Whh,
           const float* __restrict__ bias,
           float* __restrict__ h_out, float* __restrict__ c_out)
{
    __shared__ unsigned short hA[2][NBATCH][72];
    __shared__ int slen[NBATCH];

    const int tid = threadIdx.x;
    const int w = tid >> 6, L = tid & 63, lo = L & 15, hi = L >> 4;
    const int lob = lo & 7;
    const int b0 = blockIdx.x * NBATCH;

    // A-frags: lane holds Whh[gi*64 + w*16 + lo][kk*32 + hi*8 + j]
    short8 af[4][2];
    #pragma unroll
    for (int gi = 0; gi < 4; ++gi) {
        const int row = gi * 64 + w * 16 + lo;
        #pragma unroll
        for (int kk = 0; kk < 2; ++kk) {
            const float* src = Whh + (long)row * H + kk * 32 + hi * 8;
            short8 f;
            #pragma unroll
            for (int j = 0; j < 8; ++j) f[j] = (short)f2bf(src[j]);
            af[gi][kk] = f;
        }
    }
    float b_g[4][4], wi_g[4][4];
    #pragma unroll
    for (int gi = 0; gi < 4; ++gi)
        #pragma unroll
        for (int r = 0; r < 4; ++r) {
            const int row = gi * 64 + w * 16 + hi * 4 + r;
            b_g[gi][r] = bias[row];
            wi_g[gi][r] = Wih[row];
        }

    for (int i = tid; i < NBATCH * 64; i += 256) hA[0][i >> 6][i & 63] = 0;
    if (tid < NBATCH) slen[tid] = seq_len[b0 + tid];
    __syncthreads();

    int maxlen = 1;
    #pragma unroll
    for (int i = 0; i < NBATCH; ++i) maxlen = max(maxlen, slen[i]);
    const int len_lo = slen[lob];

    const float* xrow = padded + (long)(b0 + lob) * T;
    f32x4 xc = *(const f32x4*)(xrow);
    f32x4 xn = *(const f32x4*)(xrow + 4);

    float c_st[4] = {0,0,0,0}, h_st[4] = {0,0,0,0};

#define ESTEP(P, XI)                                                          \
    {                                                                         \
        const float x = xc[XI];                                               \
        short8 hb0 = *(const short8*)&hA[P][lob][hi * 8];                     \
        short8 hb1 = *(const short8*)&hA[P][lob][32 + hi * 8];                \
        f32x4 acc[4];                                                         \
        _Pragma("unroll")                                                     \
        for (int gi = 0; gi < 4; ++gi) {                                      \
            f32x4 z = {b_g[gi][0], b_g[gi][1], b_g[gi][2], b_g[gi][3]};       \
            z = __builtin_amdgcn_mfma_f32_16x16x32_bf16(af[gi][0], hb0, z, 0,0,0);       \
            acc[gi] = __builtin_amdgcn_mfma_f32_16x16x32_bf16(af[gi][1], hb1, z, 0,0,0); \
        }                                                                     \
        const bool act = (t + XI) < len_lo;                                   \
        short4v hp;                                                           \
        _Pragma("unroll")                                                     \
        for (int r = 0; r < 4; ++r) {                                         \
            float g0 = acc[0][r] + wi_g[0][r] * x;                            \
            float g1 = acc[1][r] + wi_g[1][r] * x;                            \
            float g2 = acc[2][r] + wi_g[2][r] * x;                            \
            float g3 = acc[3][r] + wi_g[3][r] * x;                            \
            float cn = sigm(g1) * c_st[r] + sigm(g0) * tanh_(g2);             \
            float hn = sigm(g3) * tanh_(cn);                                  \
            if (act) { c_st[r] = cn; h_st[r] = hn; }                          \
            hp[r] = (short)f2bf(h_st[r]);                                     \
        }                                                                     \
        if (lo < 8) *(short4v*)&hA[(P) ^ 1][lob][w * 16 + hi * 4] = hp;       \
        __syncthreads();                                                      \
    }

    for (int t = 0; t < maxlen; t += 4) {
        ESTEP(0, 0) ESTEP(1, 1) ESTEP(0, 2) ESTEP(1, 3)
        xc = xn;
        int nb = t + 8; if (nb > T - 4) nb = T - 4;
        xn = *(const f32x4*)(xrow + nb);
    }
#undef ESTEP

    if (lo < 8) {
        f32x4 hv = {h_st[0], h_st[1], h_st[2], h_st[3]};
        f32x4 cv = {c_st[0], c_st[1], c_st[2], c_st[3]};
        *(f32x4*)&h_out[(long)(b0 + lo) * H + w * 16 + hi * 4] = hv;
        *(f32x4*)&c_out[(long)(b0 + lo) * H + w * 16 + hi * 4] = cv;
    }
}

// ---------------------------------------------------------------------------
// Bottleneck + y0 correction term for the decoder's rank-1 fold.
// ---------------------------------------------------------------------------
extern "C" __global__ void __launch_bounds__(256)
mid_kernel(const float* __restrict__ h_enc,
           const float* __restrict__ eW, const float* __restrict__ eb,
           const float* __restrict__ dW, const float* __restrict__ db,
           const float* __restrict__ outW, const float* __restrict__ outb,
           float* __restrict__ hz_out, float* __restrict__ hd_out,
           float* __restrict__ y0c)
{
    int b = blockIdx.x * blockDim.x + threadIdx.x;
    if (b >= B) return;
    const float* h = h_enc + (long)b * H;
    float hz[3];
    #pragma unroll
    for (int j = 0; j < 3; ++j) {
        float s = eb[j];
        for (int k = 0; k < H; ++k) s += h[k] * eW[j*H + k];
        hz[j] = sigm(s);
        hz_out[b*3 + j] = hz[j];
    }
    float y0 = outb[0];
    for (int u = 0; u < H; ++u) {
        float hd = db[u] + hz[0]*dW[u*3] + hz[1]*dW[u*3+1] + hz[2]*dW[u*3+2];
        hd_out[(long)b*H + u] = hd;
        y0 += outW[u] * hd;
    }
    y0c[b] = y0;
}

// ---------------------------------------------------------------------------
// Decoder, rank-1 folded (W' = Whh + Wih (x) outW), 512 blocks x 8 batches.
// t=0 correction peeled out of the hot loop; y recovered one step delayed
// via 2 extra MFMAs on wave 0.
// ---------------------------------------------------------------------------
extern "C" __global__ void __launch_bounds__(256, 2)
dec_kernel(const float* __restrict__ hd, const float* __restrict__ c_in,
           const float* __restrict__ Wih, const float* __restrict__ Whh,
           const float* __restrict__ bias, const float* __restrict__ outW,
           const float* __restrict__ outb, const float* __restrict__ y0c,
           float* __restrict__ y_out)
{
    __shared__ unsigned short hA[2][NBATCH][72];

    const int tid = threadIdx.x;
    const int w = tid >> 6, L = tid & 63, lo = L & 15, hi = L >> 4;
    const int lob = lo & 7;
    const int b0 = blockIdx.x * NBATCH;

    short8 af[4][2];
    #pragma unroll
    for (int gi = 0; gi < 4; ++gi) {
        const int row = gi * 64 + w * 16 + lo;
        const float wir = Wih[row];
        #pragma unroll
        for (int kk = 0; kk < 2; ++kk) {
            const float* src = Whh + (long)row * H + kk * 32 + hi * 8;
            const float* ow  = outW + kk * 32 + hi * 8;
            short8 f;
            #pragma unroll
            for (int j = 0; j < 8; ++j) f[j] = (short)f2bf(src[j] + wir * ow[j]);
            af[gi][kk] = f;
        }
    }
    const float outb_s = outb[0];
    const float y0 = y0c[b0 + lob];
    float b_g[4][4], corr[4][4];
    #pragma unroll
    for (int gi = 0; gi < 4; ++gi)
        #pragma unroll
        for (int r = 0; r < 4; ++r) {
            const int row = gi * 64 + w * 16 + hi * 4 + r;
            const float wir = Wih[row];
            b_g[gi][r] = bias[row] + wir * outb_s;
            corr[gi][r] = wir * y0;
        }
    short8 ya[2] = { (short8)0, (short8)0 };
    if (w == 0 && lo == 0) {
        #pragma unroll
        for (int kk = 0; kk < 2; ++kk) {
            short8 f;
            #pragma unroll
            for (int j = 0; j < 8; ++j) f[j] = (short)f2bf(outW[kk*32 + hi*8 + j]);
            ya[kk] = f;
        }
    }

    for (int i = tid; i < NBATCH * 64; i += 256) {
        int m = i >> 6, k = i & 63;
        hA[0][m][k] = f2bf(hd[(long)(b0 + m) * H + k]);
    }
    float c_st[4];
    {
        f32x4 cv = *(const f32x4*)&c_in[(long)(b0 + lob) * H + w * 16 + hi * 4];
        #pragma unroll
        for (int r = 0; r < 4; ++r) c_st[r] = cv[r];
    }
    __syncthreads();

#define DSTEP(P, CORR, TT)                                                    \
    {                                                                         \
        short8 hb0 = *(const short8*)&hA[P][lob][hi * 8];                     \
        short8 hb1 = *(const short8*)&hA[P][lob][32 + hi * 8];                \
        f32x4 acc[4];                                                         \
        _Pragma("unroll")                                                     \
        for (int gi = 0; gi < 4; ++gi) {                                      \
            f32x4 z = {b_g[gi][0], b_g[gi][1], b_g[gi][2], b_g[gi][3]};       \
            z = __builtin_amdgcn_mfma_f32_16x16x32_bf16(af[gi][0], hb0, z, 0,0,0);       \
            acc[gi] = __builtin_amdgcn_mfma_f32_16x16x32_bf16(af[gi][1], hb1, z, 0,0,0); \
        }                                                                     \
        if (w == 0) {                                                         \
            f32x4 zy = {outb_s, outb_s, outb_s, outb_s};                      \
            zy = __builtin_amdgcn_mfma_f32_16x16x32_bf16(ya[0], hb0, zy, 0,0,0); \
            zy = __builtin_amdgcn_mfma_f32_16x16x32_bf16(ya[1], hb1, zy, 0,0,0); \
            if ((TT) > 0 && hi == 0 && lo < 8)                                \
                y_out[(long)(b0 + lo) * T + ((TT) - 1)] = zy[0];              \
        }                                                                     \
        if (CORR) {                                                           \
            _Pragma("unroll")                                                 \
            for (int gi = 0; gi < 4; ++gi)                                    \
                _Pragma("unroll")                                             \
                for (int r = 0; r < 4; ++r) acc[gi][r] -= corr[gi][r];        \
        }                                                                     \
        short4v hp;                                                           \
        _Pragma("unroll")                                                     \
        for (int r = 0; r < 4; ++r) {                                         \
            float cn = sigm(acc[1][r]) * c_st[r] + sigm(acc[0][r]) * tanh_(acc[2][r]); \
            float hn = sigm(acc[3][r]) * tanh_(cn);                           \
            c_st[r] = cn;                                                     \
            hp[r] = (short)f2bf(hn);                                          \
        }                                                                     \
        if (lo < 8) *(short4v*)&hA[(P) ^ 1][lob][w * 16 + hi * 4] = hp;       \
        __syncthreads();                                                      \
    }

    DSTEP(0, 1, 0) DSTEP(1, 0, 1) DSTEP(0, 0, 2) DSTEP(1, 0, 3)
    for (int t = 4; t < T; t += 4) {
        DSTEP(0, 0, t) DSTEP(1, 0, t + 1) DSTEP(0, 0, t + 2) DSTEP(1, 0, t + 3)
    }
#undef DSTEP

    if (w == 0) {       // final y_{T-1} (T even -> buffer 0)
        short8 hb0 = *(const short8*)&hA[0][lob][hi * 8];
        short8 hb1 = *(const short8*)&hA[0][lob][32 + hi * 8];
        f32x4 zy = {outb_s, outb_s, outb_s, outb_s};
        zy = __builtin_amdgcn_mfma_f32_16x16x32_bf16(ya[0], hb0, zy, 0,0,0);
        zy = __builtin_amdgcn_mfma_f32_16x16x32_bf16(ya[1], hb1, zy, 0,0,0);
        if (hi == 0 && lo < 8) y_out[(long)(b0 + lo) * T + (T - 1)] = zy[0];
    }
}

// ---------------------------------------------------------------------------
extern "C" __global__ void __launch_bounds__(256)
loss_kernel(const float* __restrict__ padded, const float* __restrict__ y,
            const int* __restrict__ seq_len, float* __restrict__ acc2)
{
    const long n4 = (long)B * T / 4;
    long i0 = (long)(blockIdx.x * blockDim.x + threadIdx.x);
    long stride = (long)gridDim.x * blockDim.x;
    float s = 0.f, cnt = 0.f;
    for (long i = i0; i < n4; i += stride) {
        int b = (int)(i >> 9);                  // T/4 = 512
        int t = (int)(i & 511) * 4;
        int len = seq_len[b];
        f32x4 pv = *(const f32x4*)&padded[i * 4];
        f32x4 yv = *(const f32x4*)&y[i * 4];
        #pragma unroll
        for (int e = 0; e < 4; ++e)
            if (t + e < len) { float d = pv[e] - yv[e]; s += d * d; cnt += 1.0f; }
    }
    for (int m = 1; m < 64; m <<= 1) { s += __shfl_xor(s, m); cnt += __shfl_xor(cnt, m); }
    if ((threadIdx.x & 63) == 0) { atomicAdd(&acc2[0], s); atomicAdd(&acc2[1], cnt); }
}

extern "C" __global__ void fin_kernel(const float* __restrict__ acc2, float* __restrict__ out)
{
    out[0] = acc2[0] / acc2[1];
}

// ---------------------------------------------------------------------------
extern "C" void kernel_launch(void* const* d_in, const int* in_sizes, int n_in,
                              void* d_out, int out_size, void* d_ws, size_t ws_size,
                              hipStream_t stream)
{
    const float* padded = (const float*)d_in[0];
    const int*   seq    = (const int*)  d_in[1];
    const float* eWih   = (const float*)d_in[2];
    const float* eWhh   = (const float*)d_in[3];
    const float* eb     = (const float*)d_in[4];
    const float* elW    = (const float*)d_in[5];
    const float* elb    = (const float*)d_in[6];
    const float* dlW    = (const float*)d_in[7];
    const float* dlb    = (const float*)d_in[8];
    const float* dWih   = (const float*)d_in[9];
    const float* dWhh   = (const float*)d_in[10];
    const float* db     = (const float*)d_in[11];
    const float* outW   = (const float*)d_in[12];
    const float* outb   = (const float*)d_in[13];
    float* out = (float*)d_out;

    float* ws    = (float*)d_ws;
    float* h_enc = ws;
    float* c_enc = ws + (long)B * H;
    float* hd    = ws + 2L * B * H;
    float* y0c   = ws + 3L * B * H;
    float* acc2  = ws + 3L * B * H + B;

    float* out_pad = out + 1;
    float* out_y   = out + 1 + (long)B * T;
    float* out_hz  = out + 1 + 2L * (long)B * T;

    hipMemcpyAsync(out_pad, padded, (long)B * T * sizeof(float),
                   hipMemcpyDeviceToDevice, stream);
    hipMemsetAsync(acc2, 0, 2 * sizeof(float), stream);

    enc_kernel<<<NB, 256, 0, stream>>>(padded, seq, eWih, eWhh, eb, h_enc, c_enc);
    mid_kernel<<<B / 256, 256, 0, stream>>>(h_enc, elW, elb, dlW, dlb, outW, outb,
                                            out_hz, hd, y0c);
    dec_kernel<<<NB, 256, 0, stream>>>(hd, c_enc, dWih, dWhh, db, outW, outb, y0c, out_y);
    loss_kernel<<<1024, 256, 0, stream>>>(padded, out_y, seq, acc2);
    fin_kernel<<<1, 1, 0, stream>>>(acc2, out);
}

// Round 4
// 2083.822 us; speedup vs baseline: 1.6653x; 1.6653x over previous
//
#include <hip/hip_runtime.h>

#define B 4096
#define T 2048
#define H 64
#define NBATCH 16
#define NB (B / NBATCH)     // 256 blocks
#define NTHREADS 512        // 8 waves -> 2 waves/SIMD, no wasted lanes

typedef __attribute__((ext_vector_type(8))) short short8;
typedef __attribute__((ext_vector_type(4))) float f32x4;

__device__ __forceinline__ float ex2(float x) { return __builtin_amdgcn_exp2f(x); }
__device__ __forceinline__ float sigm(float x) {
    return __builtin_amdgcn_rcpf(1.0f + ex2(-1.4426950408889634f * x));
}
__device__ __forceinline__ float tanh_(float x) {
    float xc = fminf(15.0f, fmaxf(-15.0f, x));
    float e = ex2(2.8853900817779268f * xc);         // e^(2x)
    return (e - 1.0f) * __builtin_amdgcn_rcpf(e + 1.0f);
}
__device__ __forceinline__ unsigned short f2bf(float f) {  // RNE f32->bf16
    unsigned u = __builtin_bit_cast(unsigned, f);
    u += 0x7fffu + ((u >> 16) & 1u);
    return (unsigned short)(u >> 16);
}
// CK-style LDS-only barrier: drains lgkm (our ds_writes) but leaves global
// loads in flight -> no vmcnt(0) HBM stall at every step barrier.
__device__ __forceinline__ void lds_barrier() {
    asm volatile("s_waitcnt lgkmcnt(0)\n\ts_barrier" ::: "memory");
}

// ---------------------------------------------------------------------------
// Encoder: 256 blocks x 512 threads (8 waves = 2/SIMD), 16 batches/block.
// Wave w owns units w*8..w*8+7 via 2 M-tiles with remapped A rows:
//   logical row of tile tt, m:  G = (m&3)*64 + (2w+tt)*4 + (m>>2)
// so lane (lo,hi) acc[tt][r] = gate r of unit (2w+tt)*4+hi, batch lo --
// all 4 gates of a unit land in one lane; 2 cells/lane/step.
// ---------------------------------------------------------------------------
extern "C" __global__ void __launch_bounds__(NTHREADS, 2)
enc_kernel(const float* __restrict__ padded, const int* __restrict__ seq_len,
           const float* __restrict__ Wih, const float* __restrict__ Whh,
           const float* __restrict__ bias,
           float* __restrict__ h_out, float* __restrict__ c_out)
{
    __shared__ unsigned short hA[2][NBATCH][72];
    __shared__ int slen[NBATCH];

    const int tid = threadIdx.x;
    const int w = tid >> 6, L = tid & 63, lo = L & 15, hi = L >> 4;
    const int b0 = blockIdx.x * NBATCH;

    // A-frags (weights, regs forever): lane holds A[m=lo][k=hi*8+j]
    short8 af[2][2];
    #pragma unroll
    for (int tt = 0; tt < 2; ++tt) {
        const int G = (lo & 3) * 64 + (2 * w + tt) * 4 + (lo >> 2);
        #pragma unroll
        for (int kk = 0; kk < 2; ++kk) {
            const float* src = Whh + (long)G * H + kk * 32 + hi * 8;
            short8 f;
            #pragma unroll
            for (int j = 0; j < 8; ++j) f[j] = (short)f2bf(src[j]);
            af[tt][kk] = f;
        }
    }
    // per-acc-row params: C row m=hi*4+r -> gate r, unit (2w+tt)*4+hi
    float b_g[2][4], wi_g[2][4];
    #pragma unroll
    for (int tt = 0; tt < 2; ++tt)
        #pragma unroll
        for (int r = 0; r < 4; ++r) {
            const int G2 = r * 64 + (2 * w + tt) * 4 + hi;
            b_g[tt][r] = bias[G2];
            wi_g[tt][r] = Wih[G2];
        }

    for (int i = tid; i < NBATCH * 64; i += NTHREADS) hA[0][i >> 6][i & 63] = 0;
    if (tid < NBATCH) slen[tid] = seq_len[b0 + tid];
    lds_barrier();

    int maxlen = 1;
    #pragma unroll
    for (int i = 0; i < NBATCH; ++i) maxlen = max(maxlen, slen[i]);
    const int len_lo = slen[lo];

    const float* xrow = padded + (long)(b0 + lo) * T;
    f32x4 xc = *(const f32x4*)(xrow);
    f32x4 xn = *(const f32x4*)(xrow + 4);

    float c_st[2] = {0, 0}, h_st[2] = {0, 0};
    const int u_unit0 = 8 * w + hi, u_unit1 = 8 * w + 4 + hi;

#define ESTEP(P, XI)                                                          \
    {                                                                         \
        const float x = xc[XI];                                               \
        short8 hb0 = *(const short8*)&hA[P][lo][hi * 8];                      \
        short8 hb1 = *(const short8*)&hA[P][lo][32 + hi * 8];                 \
        f32x4 acc[2];                                                         \
        _Pragma("unroll")                                                     \
        for (int tt = 0; tt < 2; ++tt) {                                      \
            f32x4 z = {b_g[tt][0] + wi_g[tt][0] * x,                          \
                       b_g[tt][1] + wi_g[tt][1] * x,                          \
                       b_g[tt][2] + wi_g[tt][2] * x,                          \
                       b_g[tt][3] + wi_g[tt][3] * x};                         \
            z = __builtin_amdgcn_mfma_f32_16x16x32_bf16(af[tt][0], hb0, z, 0,0,0);       \
            acc[tt] = __builtin_amdgcn_mfma_f32_16x16x32_bf16(af[tt][1], hb1, z, 0,0,0); \
        }                                                                     \
        const bool act = (t + XI) < len_lo;                                   \
        _Pragma("unroll")                                                     \
        for (int tt = 0; tt < 2; ++tt) {                                      \
            float i_ = sigm(acc[tt][0]);                                      \
            float f_ = sigm(acc[tt][1]);                                      \
            float g_ = tanh_(acc[tt][2]);                                     \
            float o_ = sigm(acc[tt][3]);                                      \
            float cn = f_ * c_st[tt] + i_ * g_;                               \
            float hn = o_ * tanh_(cn);                                        \
            if (act) { c_st[tt] = cn; h_st[tt] = hn; }                        \
        }                                                                     \
        hA[(P) ^ 1][lo][u_unit0] = f2bf(h_st[0]);                             \
        hA[(P) ^ 1][lo][u_unit1] = f2bf(h_st[1]);                             \
        lds_barrier();                                                        \
    }

    for (int t = 0; t < maxlen; t += 4) {
        int nb = t + 8; if (nb > T - 4) nb = T - 4;
        f32x4 xf = *(const f32x4*)(xrow + nb);   // 8-step-ahead prefetch
        ESTEP(0, 0) ESTEP(1, 1) ESTEP(0, 2) ESTEP(1, 3)
        xc = xn; xn = xf;
    }
#undef ESTEP

    h_out[(long)(b0 + lo) * H + u_unit0] = h_st[0];
    h_out[(long)(b0 + lo) * H + u_unit1] = h_st[1];
    c_out[(long)(b0 + lo) * H + u_unit0] = c_st[0];
    c_out[(long)(b0 + lo) * H + u_unit1] = c_st[1];
}

// ---------------------------------------------------------------------------
// Bottleneck + y0 correction term for the decoder's rank-1 fold.
// ---------------------------------------------------------------------------
extern "C" __global__ void __launch_bounds__(256)
mid_kernel(const float* __restrict__ h_enc,
           const float* __restrict__ eW, const float* __restrict__ eb,
           const float* __restrict__ dW, const float* __restrict__ db,
           const float* __restrict__ outW, const float* __restrict__ outb,
           float* __restrict__ hz_out, float* __restrict__ hd_out,
           float* __restrict__ y0c)
{
    int b = blockIdx.x * blockDim.x + threadIdx.x;
    if (b >= B) return;
    const float* h = h_enc + (long)b * H;
    float hz[3];
    #pragma unroll
    for (int j = 0; j < 3; ++j) {
        float s = eb[j];
        for (int k = 0; k < H; ++k) s += h[k] * eW[j*H + k];
        hz[j] = sigm(s);
        hz_out[b*3 + j] = hz[j];
    }
    float y0 = outb[0];
    for (int u = 0; u < H; ++u) {
        float hd = db[u] + hz[0]*dW[u*3] + hz[1]*dW[u*3+1] + hz[2]*dW[u*3+2];
        hd_out[(long)b*H + u] = hd;
        y0 += outW[u] * hd;
    }
    y0c[b] = y0;
}

// ---------------------------------------------------------------------------
// Decoder: rank-1 fold (W' = Whh + Wih (x) outW, b' = b + Wih*outb) makes it
// a pure LSTM; y_{t-1} recovered by 2 extra MFMAs on wave 0 (A row 0 = outW),
// one step delayed. t=0 correction peeled. Same 8-wave structure as encoder.
// ---------------------------------------------------------------------------
extern "C" __global__ void __launch_bounds__(NTHREADS, 2)
dec_kernel(const float* __restrict__ hd, const float* __restrict__ c_in,
           const float* __restrict__ Wih, const float* __restrict__ Whh,
           const float* __restrict__ bias, const float* __restrict__ outW,
           const float* __restrict__ outb, const float* __restrict__ y0c,
           float* __restrict__ y_out)
{
    __shared__ unsigned short hA[2][NBATCH][72];

    const int tid = threadIdx.x;
    const int w = tid >> 6, L = tid & 63, lo = L & 15, hi = L >> 4;
    const int b0 = blockIdx.x * NBATCH;

    short8 af[2][2];
    #pragma unroll
    for (int tt = 0; tt < 2; ++tt) {
        const int G = (lo & 3) * 64 + (2 * w + tt) * 4 + (lo >> 2);
        const float wir = Wih[G];
        #pragma unroll
        for (int kk = 0; kk < 2; ++kk) {
            const float* src = Whh + (long)G * H + kk * 32 + hi * 8;
            const float* ow  = outW + kk * 32 + hi * 8;
            short8 f;
            #pragma unroll
            for (int j = 0; j < 8; ++j) f[j] = (short)f2bf(src[j] + wir * ow[j]);
            af[tt][kk] = f;
        }
    }
    const float outb_s = outb[0];
    const float y0 = y0c[b0 + lo];
    float b_g[2][4], corr[2][4];
    #pragma unroll
    for (int tt = 0; tt < 2; ++tt)
        #pragma unroll
        for (int r = 0; r < 4; ++r) {
            const int G2 = r * 64 + (2 * w + tt) * 4 + hi;
            const float wir = Wih[G2];
            b_g[tt][r] = bias[G2] + wir * outb_s;
            corr[tt][r] = wir * y0;
        }
    short8 ya[2] = { (short8)0, (short8)0 };
    if (w == 0 && lo == 0) {
        #pragma unroll
        for (int kk = 0; kk < 2; ++kk) {
            short8 f;
            #pragma unroll
            for (int j = 0; j < 8; ++j) f[j] = (short)f2bf(outW[kk*32 + hi*8 + j]);
            ya[kk] = f;
        }
    }

    for (int i = tid; i < NBATCH * 64; i += NTHREADS) {
        int m = i >> 6, k = i & 63;
        hA[0][m][k] = f2bf(hd[(long)(b0 + m) * H + k]);
    }
    const int u_unit0 = 8 * w + hi, u_unit1 = 8 * w + 4 + hi;
    float c_st[2];
    c_st[0] = c_in[(long)(b0 + lo) * H + u_unit0];
    c_st[1] = c_in[(long)(b0 + lo) * H + u_unit1];
    lds_barrier();

#define DSTEP(P, CORR, TT)                                                    \
    {                                                                         \
        short8 hb0 = *(const short8*)&hA[P][lo][hi * 8];                      \
        short8 hb1 = *(const short8*)&hA[P][lo][32 + hi * 8];                 \
        f32x4 acc[2];                                                         \
        _Pragma("unroll")                                                     \
        for (int tt = 0; tt < 2; ++tt) {                                      \
            f32x4 z = {b_g[tt][0], b_g[tt][1], b_g[tt][2], b_g[tt][3]};       \
            z = __builtin_amdgcn_mfma_f32_16x16x32_bf16(af[tt][0], hb0, z, 0,0,0);       \
            acc[tt] = __builtin_amdgcn_mfma_f32_16x16x32_bf16(af[tt][1], hb1, z, 0,0,0); \
        }                                                                     \
        if (w == 0) {   /* y_{t-1} = outW.h_{t-1} + outb, off critical path */\
            f32x4 zy = {outb_s, outb_s, outb_s, outb_s};                      \
            zy = __builtin_amdgcn_mfma_f32_16x16x32_bf16(ya[0], hb0, zy, 0,0,0); \
            zy = __builtin_amdgcn_mfma_f32_16x16x32_bf16(ya[1], hb1, zy, 0,0,0); \
            if ((TT) > 0 && hi == 0)                                          \
                y_out[(long)(b0 + lo) * T + ((TT) - 1)] = zy[0];              \
        }                                                                     \
        if (CORR) {                                                           \
            _Pragma("unroll")                                                 \
            for (int tt = 0; tt < 2; ++tt)                                    \
                _Pragma("unroll")                                             \
                for (int r = 0; r < 4; ++r) acc[tt][r] -= corr[tt][r];        \
        }                                                                     \
        _Pragma("unroll")                                                     \
        for (int tt = 0; tt < 2; ++tt) {                                      \
            float i_ = sigm(acc[tt][0]);                                      \
            float f_ = sigm(acc[tt][1]);                                      \
            float g_ = tanh_(acc[tt][2]);                                     \
            float o_ = sigm(acc[tt][3]);                                      \
            float cn = f_ * c_st[tt] + i_ * g_;                               \
            float hn = o_ * tanh_(cn);                                        \
            c_st[tt] = cn;                                                    \
            hA[(P) ^ 1][lo][tt ? u_unit1 : u_unit0] = f2bf(hn);               \
        }                                                                     \
        lds_barrier();                                                        \
    }

    DSTEP(0, 1, 0) DSTEP(1, 0, 1) DSTEP(0, 0, 2) DSTEP(1, 0, 3)
    for (int t = 4; t < T; t += 4) {
        DSTEP(0, 0, t) DSTEP(1, 0, t + 1) DSTEP(0, 0, t + 2) DSTEP(1, 0, t + 3)
    }
#undef DSTEP

    if (w == 0) {       // final y_{T-1} (T even -> parity 0)
        short8 hb0 = *(const short8*)&hA[0][lo][hi * 8];
        short8 hb1 = *(const short8*)&hA[0][lo][32 + hi * 8];
        f32x4 zy = {outb_s, outb_s, outb_s, outb_s};
        zy = __builtin_amdgcn_mfma_f32_16x16x32_bf16(ya[0], hb0, zy, 0,0,0);
        zy = __builtin_amdgcn_mfma_f32_16x16x32_bf16(ya[1], hb1, zy, 0,0,0);
        if (hi == 0) y_out[(long)(b0 + lo) * T + (T - 1)] = zy[0];
    }
}

// ---------------------------------------------------------------------------
extern "C" __global__ void __launch_bounds__(256)
loss_kernel(const float* __restrict__ padded, const float* __restrict__ y,
            const int* __restrict__ seq_len, float* __restrict__ acc2)
{
    const long n4 = (long)B * T / 4;
    long i0 = (long)(blockIdx.x * blockDim.x + threadIdx.x);
    long stride = (long)gridDim.x * blockDim.x;
    float s = 0.f, cnt = 0.f;
    for (long i = i0; i < n4; i += stride) {
        int b = (int)(i >> 9);                  // T/4 = 512
        int t = (int)(i & 511) * 4;
        int len = seq_len[b];
        f32x4 pv = *(const f32x4*)&padded[i * 4];
        f32x4 yv = *(const f32x4*)&y[i * 4];
        #pragma unroll
        for (int e = 0; e < 4; ++e)
            if (t + e < len) { float d = pv[e] - yv[e]; s += d * d; cnt += 1.0f; }
    }
    for (int m = 1; m < 64; m <<= 1) { s += __shfl_xor(s, m); cnt += __shfl_xor(cnt, m); }
    if ((threadIdx.x & 63) == 0) { atomicAdd(&acc2[0], s); atomicAdd(&acc2[1], cnt); }
}

extern "C" __global__ void fin_kernel(const float* __restrict__ acc2, float* __restrict__ out)
{
    out[0] = acc2[0] / acc2[1];
}

// ---------------------------------------------------------------------------
extern "C" void kernel_launch(void* const* d_in, const int* in_sizes, int n_in,
                              void* d_out, int out_size, void* d_ws, size_t ws_size,
                              hipStream_t stream)
{
    const float* padded = (const float*)d_in[0];
    const int*   seq    = (const int*)  d_in[1];
    const float* eWih   = (const float*)d_in[2];
    const float* eWhh   = (const float*)d_in[3];
    const float* eb     = (const float*)d_in[4];
    const float* elW    = (const float*)d_in[5];
    const float* elb    = (const float*)d_in[6];
    const float* dlW    = (const float*)d_in[7];
    const float* dlb    = (const float*)d_in[8];
    const float* dWih   = (const float*)d_in[9];
    const float* dWhh   = (const float*)d_in[10];
    const float* db     = (const float*)d_in[11];
    const float* outW   = (const float*)d_in[12];
    const float* outb   = (const float*)d_in[13];
    float* out = (float*)d_out;

    float* ws    = (float*)d_ws;
    float* h_enc = ws;
    float* c_enc = ws + (long)B * H;
    float* hd    = ws + 2L * B * H;
    float* y0c   = ws + 3L * B * H;
    float* acc2  = ws + 3L * B * H + B;

    float* out_pad = out + 1;
    float* out_y   = out + 1 + (long)B * T;
    float* out_hz  = out + 1 + 2L * (long)B * T;

    hipMemcpyAsync(out_pad, padded, (long)B * T * sizeof(float),
                   hipMemcpyDeviceToDevice, stream);
    hipMemsetAsync(acc2, 0, 2 * sizeof(float), stream);

    enc_kernel<<<NB, NTHREADS, 0, stream>>>(padded, seq, eWih, eWhh, eb, h_enc, c_enc);
    mid_kernel<<<B / 256, 256, 0, stream>>>(h_enc, elW, elb, dlW, dlb, outW, outb,
                                            out_hz, hd, y0c);
    dec_kernel<<<NB, NTHREADS, 0, stream>>>(hd, c_enc, dWih, dWhh, db, outW, outb, y0c, out_y);
    loss_kernel<<<1024, 256, 0, stream>>>(padded, out_y, seq, acc2);
    fin_kernel<<<1, 1, 0, stream>>>(acc2, out);
}

// Round 5
// 2001.165 us; speedup vs baseline: 1.7341x; 1.0413x over previous
//
#include <hip/hip_runtime.h>

#define B 4096
#define T 2048
#define H 64
#define NBATCH 16
#define NB (B / NBATCH)     // 256 blocks, 1 per CU
#define NTHREADS 1024       // 16 waves -> 4 waves/SIMD, 1 cell/lane

typedef __attribute__((ext_vector_type(8))) short short8;
typedef __attribute__((ext_vector_type(4))) float f32x4;

__device__ __forceinline__ float ex2(float x) { return __builtin_amdgcn_exp2f(x); }
__device__ __forceinline__ float sigm(float x) {
    return __builtin_amdgcn_rcpf(1.0f + ex2(-1.4426950408889634f * x));
}
__device__ __forceinline__ float tanh_(float x) {
    float xc = fminf(15.0f, fmaxf(-15.0f, x));
    float e = ex2(2.8853900817779268f * xc);         // e^(2x)
    return (e - 1.0f) * __builtin_amdgcn_rcpf(e + 1.0f);
}
__device__ __forceinline__ unsigned short f2bf(float f) {  // RNE f32->bf16
    unsigned u = __builtin_bit_cast(unsigned, f);
    u += 0x7fffu + ((u >> 16) & 1u);
    return (unsigned short)(u >> 16);
}
// LDS-only barrier: drain lgkm (ds ops) but leave global loads in flight.
__device__ __forceinline__ void lds_barrier() {
    asm volatile("s_waitcnt lgkmcnt(0)\n\ts_barrier" ::: "memory");
}

// ---------------------------------------------------------------------------
// Encoder: 256 blocks x 1024 threads (16 waves = 4/SIMD), 16 batches/block,
// 1 cell/lane. Wave w owns units w*4..w*4+3 via remapped A rows:
//   G(m) = (m&3)*64 + w*4 + (m>>2)
// C row hi*4+r = gate r of unit w*4+hi, col = batch lo. One b16 write/lane.
// ---------------------------------------------------------------------------
extern "C" __global__ void __launch_bounds__(NTHREADS, 1)
enc_kernel(const float* __restrict__ padded, const int* __restrict__ seq_len,
           const float* __restrict__ Wih, const float* __restrict__ Whh,
           const float* __restrict__ bias,
           float* __restrict__ h_out, float* __restrict__ c_out)
{
    __shared__ unsigned short hA[2][NBATCH][72];
    __shared__ int slen[NBATCH];

    const int tid = threadIdx.x;
    const int w = tid >> 6, L = tid & 63, lo = L & 15, hi = L >> 4;
    const int b0 = blockIdx.x * NBATCH;
    const int unit = w * 4 + hi;

    // A-frag (weights, regs forever): lane holds A[m=lo][k=hi*8+j] of the
    // remapped 16x64 tile.
    short8 af[2];
    {
        const int G = (lo & 3) * 64 + w * 4 + (lo >> 2);
        #pragma unroll
        for (int kk = 0; kk < 2; ++kk) {
            const float* src = Whh + (long)G * H + kk * 32 + hi * 8;
            short8 f;
            #pragma unroll
            for (int j = 0; j < 8; ++j) f[j] = (short)f2bf(src[j]);
            af[kk] = f;
        }
    }
    float b_g[4], wi_g[4];
    #pragma unroll
    for (int r = 0; r < 4; ++r) {
        const int G2 = r * 64 + unit;
        b_g[r] = bias[G2];
        wi_g[r] = Wih[G2];
    }

    if (tid < NBATCH * 64) hA[0][tid >> 6][tid & 63] = 0;
    if (tid < NBATCH) slen[tid] = seq_len[b0 + tid];
    lds_barrier();

    int maxlen = 1;
    #pragma unroll
    for (int i = 0; i < NBATCH; ++i) maxlen = max(maxlen, slen[i]);
    const int len_lo = slen[lo];

    const float* xrow = padded + (long)(b0 + lo) * T;
    f32x4 xc = *(const f32x4*)(xrow);
    f32x4 xn = *(const f32x4*)(xrow + 4);

    float c_st = 0.f, h_st = 0.f;

#define ESTEP(P, XI)                                                          \
    {                                                                         \
        const float x = xc[XI];                                               \
        short8 hb0 = *(const short8*)&hA[P][lo][hi * 8];                      \
        short8 hb1 = *(const short8*)&hA[P][lo][32 + hi * 8];                 \
        f32x4 z = {b_g[0] + wi_g[0] * x, b_g[1] + wi_g[1] * x,                \
                   b_g[2] + wi_g[2] * x, b_g[3] + wi_g[3] * x};               \
        z = __builtin_amdgcn_mfma_f32_16x16x32_bf16(af[0], hb0, z, 0,0,0);    \
        f32x4 acc = __builtin_amdgcn_mfma_f32_16x16x32_bf16(af[1], hb1, z, 0,0,0); \
        const bool act = (t + XI) < len_lo;                                   \
        float i_ = sigm(acc[0]);                                              \
        float f_ = sigm(acc[1]);                                              \
        float g_ = tanh_(acc[2]);                                             \
        float o_ = sigm(acc[3]);                                              \
        float cn = f_ * c_st + i_ * g_;                                       \
        float hn = o_ * tanh_(cn);                                            \
        if (act) { c_st = cn; h_st = hn; }                                    \
        hA[(P) ^ 1][lo][unit] = f2bf(h_st);                                   \
        lds_barrier();                                                        \
    }

    for (int t = 0; t < maxlen; t += 4) {
        int nb = t + 8; if (nb > T - 4) nb = T - 4;
        f32x4 xf = *(const f32x4*)(xrow + nb);   // 8-step-ahead prefetch
        ESTEP(0, 0) ESTEP(1, 1) ESTEP(0, 2) ESTEP(1, 3)
        xc = xn; xn = xf;
    }
#undef ESTEP

    h_out[(long)(b0 + lo) * H + unit] = h_st;
    c_out[(long)(b0 + lo) * H + unit] = c_st;
}

// ---------------------------------------------------------------------------
// Bottleneck + y0 correction term for the decoder's rank-1 fold.
// ---------------------------------------------------------------------------
extern "C" __global__ void __launch_bounds__(256)
mid_kernel(const float* __restrict__ h_enc,
           const float* __restrict__ eW, const float* __restrict__ eb,
           const float* __restrict__ dW, const float* __restrict__ db,
           const float* __restrict__ outW, const float* __restrict__ outb,
           float* __restrict__ hz_out, float* __restrict__ hd_out,
           float* __restrict__ y0c)
{
    int b = blockIdx.x * blockDim.x + threadIdx.x;
    if (b >= B) return;
    const float* h = h_enc + (long)b * H;
    float hz[3];
    #pragma unroll
    for (int j = 0; j < 3; ++j) {
        float s = eb[j];
        for (int k = 0; k < H; ++k) s += h[k] * eW[j*H + k];
        hz[j] = sigm(s);
        hz_out[b*3 + j] = hz[j];
    }
    float y0 = outb[0];
    for (int u = 0; u < H; ++u) {
        float hd = db[u] + hz[0]*dW[u*3] + hz[1]*dW[u*3+1] + hz[2]*dW[u*3+2];
        hd_out[(long)b*H + u] = hd;
        y0 += outW[u] * hd;
    }
    y0c[b] = y0;
}

// ---------------------------------------------------------------------------
// Decoder: rank-1 fold (W' = Whh + Wih (x) outW, b' = b + Wih*outb) -> pure
// LSTM. y_{t-1} recovered via 2 extra MFMAs rotating across waves (w==t&15),
// one step delayed. t=0 correction peeled. 1024 threads, 1 cell/lane.
// ---------------------------------------------------------------------------
extern "C" __global__ void __launch_bounds__(NTHREADS, 1)
dec_kernel(const float* __restrict__ hd, const float* __restrict__ c_in,
           const float* __restrict__ Wih, const float* __restrict__ Whh,
           const float* __restrict__ bias, const float* __restrict__ outW,
           const float* __restrict__ outb, const float* __restrict__ y0c,
           float* __restrict__ y_out)
{
    __shared__ unsigned short hA[2][NBATCH][72];

    const int tid = threadIdx.x;
    const int w = tid >> 6, L = tid & 63, lo = L & 15, hi = L >> 4;
    const int b0 = blockIdx.x * NBATCH;
    const int unit = w * 4 + hi;

    short8 af[2];
    {
        const int G = (lo & 3) * 64 + w * 4 + (lo >> 2);
        const float wir = Wih[G];
        #pragma unroll
        for (int kk = 0; kk < 2; ++kk) {
            const float* src = Whh + (long)G * H + kk * 32 + hi * 8;
            const float* ow  = outW + kk * 32 + hi * 8;
            short8 f;
            #pragma unroll
            for (int j = 0; j < 8; ++j) f[j] = (short)f2bf(src[j] + wir * ow[j]);
            af[kk] = f;
        }
    }
    const float outb_s = outb[0];
    const float y0 = y0c[b0 + lo];
    float b_g[4], corr[4];
    #pragma unroll
    for (int r = 0; r < 4; ++r) {
        const int G2 = r * 64 + unit;
        const float wir = Wih[G2];
        b_g[r] = bias[G2] + wir * outb_s;
        corr[r] = wir * y0;
    }
    short8 ya[2];   // y-extraction A-frag: row 0 = outW, rows 1..15 = 0
    #pragma unroll
    for (int kk = 0; kk < 2; ++kk) {
        short8 f = (short8)0;
        if (lo == 0)
            #pragma unroll
            for (int j = 0; j < 8; ++j) f[j] = (short)f2bf(outW[kk*32 + hi*8 + j]);
        ya[kk] = f;
    }

    if (tid < NBATCH * 64) {
        int m = tid >> 6, k = tid & 63;
        hA[0][m][k] = f2bf(hd[(long)(b0 + m) * H + k]);
    }
    float c_st = c_in[(long)(b0 + lo) * H + unit];
    lds_barrier();

#define DSTEP(P, CORR, TT)                                                    \
    {                                                                         \
        short8 hb0 = *(const short8*)&hA[P][lo][hi * 8];                      \
        short8 hb1 = *(const short8*)&hA[P][lo][32 + hi * 8];                 \
        f32x4 z = {b_g[0], b_g[1], b_g[2], b_g[3]};                           \
        z = __builtin_amdgcn_mfma_f32_16x16x32_bf16(af[0], hb0, z, 0,0,0);    \
        f32x4 acc = __builtin_amdgcn_mfma_f32_16x16x32_bf16(af[1], hb1, z, 0,0,0); \
        if (w == ((TT) & 15)) {  /* y_{t-1} = outW.h_{t-1}+outb, rotated */   \
            f32x4 zy = {outb_s, outb_s, outb_s, outb_s};                      \
            zy = __builtin_amdgcn_mfma_f32_16x16x32_bf16(ya[0], hb0, zy, 0,0,0); \
            zy = __builtin_amdgcn_mfma_f32_16x16x32_bf16(ya[1], hb1, zy, 0,0,0); \
            if ((TT) > 0 && hi == 0)                                          \
                y_out[(long)(b0 + lo) * T + ((TT) - 1)] = zy[0];              \
        }                                                                     \
        if (CORR) {                                                           \
            _Pragma("unroll")                                                 \
            for (int r = 0; r < 4; ++r) acc[r] -= corr[r];                    \
        }                                                                     \
        float i_ = sigm(acc[0]);                                              \
        float f_ = sigm(acc[1]);                                              \
        float g_ = tanh_(acc[2]);                                             \
        float o_ = sigm(acc[3]);                                              \
        float cn = f_ * c_st + i_ * g_;                                       \
        float hn = o_ * tanh_(cn);                                            \
        c_st = cn;                                                            \
        hA[(P) ^ 1][lo][unit] = f2bf(hn);                                     \
        lds_barrier();                                                        \
    }

    DSTEP(0, 1, 0) DSTEP(1, 0, 1) DSTEP(0, 0, 2) DSTEP(1, 0, 3)
    for (int t = 4; t < T; t += 4) {
        DSTEP(0, 0, t) DSTEP(1, 0, t + 1) DSTEP(0, 0, t + 2) DSTEP(1, 0, t + 3)
    }
#undef DSTEP

    if (w == 0) {       // final y_{T-1} (T even -> parity 0)
        short8 hb0 = *(const short8*)&hA[0][lo][hi * 8];
        short8 hb1 = *(const short8*)&hA[0][lo][32 + hi * 8];
        f32x4 zy = {outb_s, outb_s, outb_s, outb_s};
        zy = __builtin_amdgcn_mfma_f32_16x16x32_bf16(ya[0], hb0, zy, 0,0,0);
        zy = __builtin_amdgcn_mfma_f32_16x16x32_bf16(ya[1], hb1, zy, 0,0,0);
        if (hi == 0) y_out[(long)(b0 + lo) * T + (T - 1)] = zy[0];
    }
}

// ---------------------------------------------------------------------------
extern "C" __global__ void __launch_bounds__(256)
loss_kernel(const float* __restrict__ padded, const float* __restrict__ y,
            const int* __restrict__ seq_len, float* __restrict__ acc2)
{
    const long n4 = (long)B * T / 4;
    long i0 = (long)(blockIdx.x * blockDim.x + threadIdx.x);
    long stride = (long)gridDim.x * blockDim.x;
    float s = 0.f, cnt = 0.f;
    for (long i = i0; i < n4; i += stride) {
        int b = (int)(i >> 9);                  // T/4 = 512
        int t = (int)(i & 511) * 4;
        int len = seq_len[b];
        f32x4 pv = *(const f32x4*)&padded[i * 4];
        f32x4 yv = *(const f32x4*)&y[i * 4];
        #pragma unroll
        for (int e = 0; e < 4; ++e)
            if (t + e < len) { float d = pv[e] - yv[e]; s += d * d; cnt += 1.0f; }
    }
    for (int m = 1; m < 64; m <<= 1) { s += __shfl_xor(s, m); cnt += __shfl_xor(cnt, m); }
    if ((threadIdx.x & 63) == 0) { atomicAdd(&acc2[0], s); atomicAdd(&acc2[1], cnt); }
}

extern "C" __global__ void fin_kernel(const float* __restrict__ acc2, float* __restrict__ out)
{
    out[0] = acc2[0] / acc2[1];
}

// ---------------------------------------------------------------------------
extern "C" void kernel_launch(void* const* d_in, const int* in_sizes, int n_in,
                              void* d_out, int out_size, void* d_ws, size_t ws_size,
                              hipStream_t stream)
{
    const float* padded = (const float*)d_in[0];
    const int*   seq    = (const int*)  d_in[1];
    const float* eWih   = (const float*)d_in[2];
    const float* eWhh   = (const float*)d_in[3];
    const float* eb     = (const float*)d_in[4];
    const float* elW    = (const float*)d_in[5];
    const float* elb    = (const float*)d_in[6];
    const float* dlW    = (const float*)d_in[7];
    const float* dlb    = (const float*)d_in[8];
    const float* dWih   = (const float*)d_in[9];
    const float* dWhh   = (const float*)d_in[10];
    const float* db     = (const float*)d_in[11];
    const float* outW   = (const float*)d_in[12];
    const float* outb   = (const float*)d_in[13];
    float* out = (float*)d_out;

    float* ws    = (float*)d_ws;
    float* h_enc = ws;
    float* c_enc = ws + (long)B * H;
    float* hd    = ws + 2L * B * H;
    float* y0c   = ws + 3L * B * H;
    float* acc2  = ws + 3L * B * H + B;

    float* out_pad = out + 1;
    float* out_y   = out + 1 + (long)B * T;
    float* out_hz  = out + 1 + 2L * (long)B * T;

    hipMemcpyAsync(out_pad, padded, (long)B * T * sizeof(float),
                   hipMemcpyDeviceToDevice, stream);
    hipMemsetAsync(acc2, 0, 2 * sizeof(float), stream);

    enc_kernel<<<NB, NTHREADS, 0, stream>>>(padded, seq, eWih, eWhh, eb, h_enc, c_enc);
    mid_kernel<<<B / 256, 256, 0, stream>>>(h_enc, elW, elb, dlW, dlb, outW, outb,
                                            out_hz, hd, y0c);
    dec_kernel<<<NB, NTHREADS, 0, stream>>>(hd, c_enc, dWih, dWhh, db, outW, outb, y0c, out_y);
    loss_kernel<<<1024, 256, 0, stream>>>(padded, out_y, seq, acc2);
    fin_kernel<<<1, 1, 0, stream>>>(acc2, out);
}